// Round 19
// baseline (108.620 us; speedup 1.0000x reference)
//
#include <hip/hip_runtime.h>
#include <stdint.h>

// BitNetLinear eval forward on MI355X (gfx950).
// M = B*S = 32768, K = 1024 (in_features), N = 1024 (out_features).
//
// R18 = R17/R10 (pinned best, 103.1us) + ONE register-neutral change:
// non-temporal C-stores in the epilogue. Theory: kfused's 131MB C-write
// evicts the L3-resident x (128MB) mid-GEMM -> 75MB of avoidable HBM
// fetch. nt stores bypass L3 allocation; C is write-once/never-re-read.
//
// PINNED STRUCTURE — verified by 7 failed variants (do not touch):
//  - quant FIRST in tile body (R16 reorder -> +8 VGPR -> cliff)
//  - rintf+cvt+shift/or quant formulation (R12/R13 -> +4 VGPR -> cliff)
//  - BN=256 (R15's BN=128 -> per-tile overhead dominates)
//  - B via global_load_lds + counted vmcnt(2) (R5-R8 reg-B all regressed)

#define MK_M 32768
#define MK_K 1024
#define MK_N 1024

typedef __attribute__((ext_vector_type(4))) int int32x4;

// ---- workspace layout ----
#define WS_MAXP_OFF 64
#define WS_PART_OFF 8448
#define WS_QW_OFF 16384
#define WS_NEEDED (WS_QW_OFF + (1 << 20))

// fused: blocks [0,2048) -> per-block max|x|; blocks [2048,2112) -> partial sum|W|
__global__ void kprep(const float4* __restrict__ x4, const float4* __restrict__ w4,
                      float* __restrict__ maxp, double* __restrict__ partials, long n4x) {
    const int bid = blockIdx.x;
    if (bid < 2048) {
        float m = 0.f;
        const long stride = 2048L * 256;
        for (long i = (long)bid * 256 + threadIdx.x; i < n4x; i += stride) {
            float4 v = x4[i];
            m = fmaxf(m, fmaxf(fmaxf(fabsf(v.x), fabsf(v.y)), fmaxf(fabsf(v.z), fabsf(v.w))));
        }
        #pragma unroll
        for (int off = 1; off < 64; off <<= 1) m = fmaxf(m, __shfl_xor(m, off));
        __shared__ float sm[4];
        int lane = threadIdx.x & 63, wid = threadIdx.x >> 6;
        if (lane == 0) sm[wid] = m;
        __syncthreads();
        if (threadIdx.x == 0) maxp[bid] = fmaxf(fmaxf(sm[0], sm[1]), fmaxf(sm[2], sm[3]));
    } else {
        double s = 0.0;
        for (int i = (bid - 2048) * 256 + threadIdx.x; i < (1 << 18); i += 64 * 256) {
            float4 v = w4[i];
            s += (double)fabsf(v.x);
            s += (double)fabsf(v.y);
            s += (double)fabsf(v.z);
            s += (double)fabsf(v.w);
        }
        __shared__ double sd[256];
        sd[threadIdx.x] = s;
        __syncthreads();
        for (int h = 128; h > 0; h >>= 1) {
            if ((int)threadIdx.x < h) sd[threadIdx.x] += sd[threadIdx.x + h];
            __syncthreads();
        }
        if (threadIdx.x == 0) partials[bid - 2048] = sd[0];
    }
}

// every block redundantly reduces partials[64] in the SAME fixed order.
__global__ void kquant_w(const float4* __restrict__ w4, unsigned* __restrict__ qw,
                         const double* __restrict__ partials, float* __restrict__ wscp) {
    __shared__ double sws;
    if (threadIdx.x < 64) {
        double s = partials[threadIdx.x];
        #pragma unroll
        for (int off = 1; off < 64; off <<= 1) s += __shfl_xor(s, off);
        if (threadIdx.x == 0) sws = s;
    }
    __syncthreads();
    float wsc = (float)(sws / 1048576.0);   // mean|W| over 2^20 elements
    if (blockIdx.x == 0 && threadIdx.x == 0) *wscp = wsc;
    float thr = 0.5f * wsc;
    int stride = gridDim.x * blockDim.x;
    for (int i = blockIdx.x * blockDim.x + threadIdx.x; i < (1 << 18); i += stride) {
        float4 v = w4[i];
        int q0 = (fabsf(v.x) > thr) ? (v.x > 0.f ? 1 : -1) : 0;
        int q1 = (fabsf(v.y) > thr) ? (v.y > 0.f ? 1 : -1) : 0;
        int q2 = (fabsf(v.z) > thr) ? (v.z > 0.f ? 1 : -1) : 0;
        int q3 = (fabsf(v.w) > thr) ? (v.w > 0.f ? 1 : -1) : 0;
        qw[i] = (q0 & 0xff) | ((q1 & 0xff) << 8) | ((q2 & 0xff) << 16) | ((q3 & 0xff) << 24);
    }
}

// ---- fused quant-A + int8 GEMM (R10, best) ----
// Tile 128x256, BK=64, 8 waves (2Mx4N), wave = 64x64 (acc[4][4]).
__global__ __launch_bounds__(512, 2) void kfused(
    const float* __restrict__ x, const char* __restrict__ qw,
    const float* __restrict__ bias, const float* __restrict__ wscp,
    const float* __restrict__ maxp, float* __restrict__ out)
{
    __shared__ __align__(16) char As[2][8192];
    __shared__ __align__(16) char Bs[3][16384];
    __shared__ float smx[8];

    const int t = threadIdx.x;
    const int l = t & 63;
    const int w = t >> 6;          // 0..7
    const int wm = w >> 2;         // 0..1
    const int wn = w & 3;          // 0..3

    // XCD-bijective swizzle: 1024 blocks, 8 XCDs, 128 contiguous per XCD.
    const int bid = blockIdx.x;
    const int wg = (bid & 7) * 128 + (bid >> 3);
    const int tm = wg >> 2, tn = wg & 3;
    const long m0 = (long)tm * 128;
    const int n0 = tn * 256;

    // i_scale: redundant deterministic reduce of maxp[2048]
    float m = 0.f;
    #pragma unroll
    for (int j = 0; j < 4; ++j) m = fmaxf(m, maxp[t + 512 * j]);
    #pragma unroll
    for (int off = 1; off < 64; off <<= 1) m = fmaxf(m, __shfl_xor(m, off));
    if (l == 0) smx[w] = m;
    __syncthreads();
    const float mm = fmaxf(fmaxf(fmaxf(smx[0], smx[1]), fmaxf(smx[2], smx[3])),
                           fmaxf(fmaxf(smx[4], smx[5]), fmaxf(smx[6], smx[7])));
    const float isc = mm / 127.0f;
    const float rin = 1.0f / isc;

    // A staging: thread t -> row arow = t>>2 (0..127), 16 floats at k-offset
    // (t&3)*16 within each 64-float K-window.
    const int arow = t >> 2;
    const int ac = t & 3;
    const float4* gA4 = (const float4*)(x + (m0 + arow) * MK_K + ac * 16);
    const int adsw = (ac ^ ((arow >> 1) & 3));          // swizzled chunk
    char* const adst0 = (char*)As[0] + arow * 64 + adsw * 16;
    char* const adst1 = (char*)As[1] + arow * 64 + adsw * 16;

    // B staging (R2 pattern): unit = 128 rows x 64B = 8KB = 512thr x 16B
    const int gch = (t & 3) ^ ((t >> 3) & 3);
    const char* gBt = qw + ((long)n0 + (t >> 2)) * MK_K + gch * 16;
    auto stageB = [&](int kt1, int b) {
        char* dst = (char*)Bs[b] + t * 16;
        const char* src = gBt + kt1 * 64;
        __builtin_amdgcn_global_load_lds(
            (const __attribute__((address_space(1))) void*)src,
            (__attribute__((address_space(3))) void*)dst, 16, 0, 0);
        __builtin_amdgcn_global_load_lds(
            (const __attribute__((address_space(1))) void*)(src + 128L * MK_K),
            (__attribute__((address_space(3))) void*)(dst + 8192), 16, 0, 0);
    };

    float4 ar0, ar1, ar2, ar3;   // in-flight A fp32 (16 VGPR)
    auto issueA = [&](int kt1) {
        ar0 = gA4[kt1 * 16 + 0];
        ar1 = gA4[kt1 * 16 + 1];
        ar2 = gA4[kt1 * 16 + 2];
        ar3 = gA4[kt1 * 16 + 3];
    };
    auto quantA = [&](char* dst) {
        int p[4];
        float4 vv[4] = {ar0, ar1, ar2, ar3};
        #pragma unroll
        for (int q = 0; q < 4; ++q) {
            int i0 = (int)rintf(vv[q].x * rin);
            int i1 = (int)rintf(vv[q].y * rin);
            int i2 = (int)rintf(vv[q].z * rin);
            int i3 = (int)rintf(vv[q].w * rin);
            p[q] = (i0 & 0xff) | ((i1 & 0xff) << 8) | ((i2 & 0xff) << 16) | ((i3 & 0xff) << 24);
        }
        int32x4 pk = {p[0], p[1], p[2], p[3]};
        *(int32x4*)dst = pk;
    };

    int32x4 acc[4][4];
    #pragma unroll
    for (int mi = 0; mi < 4; ++mi)
        #pragma unroll
        for (int ni = 0; ni < 4; ++ni) acc[mi][ni] = (int32x4)0;

    // prologue: queue must end as [B(0)2, A(1)4, B(1)2]
    issueA(0);                 // A(0) [4]
    stageB(0, 0);              // B(0) [2]
    asm volatile("s_waitcnt vmcnt(2)" ::: "memory");   // A(0) done
    quantA(adst0);             // As[0] = A(0)
    issueA(1);                 // A(1) [4]
    stageB(1, 1);              // B(1) [2]

    for (int kt = 0; kt < 16; ++kt) {
        if (kt < 15) asm volatile("s_waitcnt vmcnt(2) lgkmcnt(0)" ::: "memory");
        else         asm volatile("s_waitcnt vmcnt(0) lgkmcnt(0)" ::: "memory");
        __builtin_amdgcn_s_barrier();

        if (kt < 15) quantA((kt & 1) ? adst0 : adst1);  // write A(kt+1) -> As[(kt+1)&1]
        if (kt < 14) {
            issueA(kt + 2);                              // A first (queue order!)
            stageB(kt + 2, (kt + 2) % 3);                // then B
        }

        const char* bufA = As[kt & 1];
        const char* bufB = Bs[kt % 3];
        int32x4 af[4], bf[4];
        #pragma unroll
        for (int i = 0; i < 4; ++i) {
            int row = wm * 64 + i * 16 + (l & 15);
            int ch = (l >> 4) ^ ((row >> 1) & 3);
            af[i] = *(const int32x4*)(bufA + row * 64 + ch * 16);
        }
        #pragma unroll
        for (int i = 0; i < 4; ++i) {
            int row = wn * 64 + i * 16 + (l & 15);
            int ch = (l >> 4) ^ ((row >> 1) & 3);
            bf[i] = *(const int32x4*)(bufB + row * 64 + ch * 16);
        }
        __builtin_amdgcn_s_setprio(1);
        #pragma unroll
        for (int mi = 0; mi < 4; ++mi)
            #pragma unroll
            for (int ni = 0; ni < 4; ++ni)
                acc[mi][ni] = __builtin_amdgcn_mfma_i32_16x16x64_i8(
                    af[mi], bf[ni], acc[mi][ni], 0, 0, 0);
        __builtin_amdgcn_s_setprio(0);
    }

    // epilogue: C/D layout col = lane&15, row = (lane>>4)*4 + reg (verified)
    // NT stores: C is write-once/never-re-read; keep it out of L3 so x stays
    // resident for the remaining blocks (R18's one change).
    const float wsc = *wscp;
    const int crow = (l >> 4) * 4;
    const int ccol = l & 15;
    #pragma unroll
    for (int mi = 0; mi < 4; ++mi) {
        #pragma unroll
        for (int ni = 0; ni < 4; ++ni) {
            long r0 = m0 + wm * 64 + mi * 16 + crow;
            int c = n0 + wn * 64 + ni * 16 + ccol;
            float b = bias[c];
            #pragma unroll
            for (int j = 0; j < 4; ++j) {
                float v = ((float)acc[mi][ni][j] * wsc) * isc + b;
                __builtin_nontemporal_store(v, &out[(r0 + j) * MK_N + c]);
            }
        }
    }
}

extern "C" void kernel_launch(void* const* d_in, const int* in_sizes, int n_in,
                              void* d_out, int out_size, void* d_ws, size_t ws_size,
                              hipStream_t stream) {
    const float* x = (const float*)d_in[0];
    const float* wt = (const float*)d_in[1];
    const float* bias = (const float*)d_in[2];
    float* out = (float*)d_out;

    if (ws_size < WS_NEEDED) return;

    char* ws = (char*)d_ws;
    float* wscp = (float*)(ws + 0);
    float* maxp = (float*)(ws + WS_MAXP_OFF);
    double* partials = (double*)(ws + WS_PART_OFF);
    char* qw = ws + WS_QW_OFF;

    const long n_x = (long)in_sizes[0];   // 33554432
    const long n4_x = n_x >> 2;

    kprep<<<2112, 256, 0, stream>>>((const float4*)x, (const float4*)wt, maxp, partials, n4_x);
    kquant_w<<<256, 256, 0, stream>>>((const float4*)wt, (unsigned*)qw, partials, wscp);

    const int grid = (MK_M / 128) * (MK_N / 256);  // 1024
    kfused<<<grid, 512, 0, stream>>>(x, qw, bias, wscp, maxp, out);
}

// Round 20
// 103.000 us; speedup vs baseline: 1.0546x; 1.0546x over previous
//
#include <hip/hip_runtime.h>
#include <stdint.h>

// BitNetLinear eval forward on MI355X (gfx950).
// M = B*S = 32768, K = 1024 (in_features), N = 1024 (out_features).
//
// R19 = R17 = R14 = R10 byte-identical (pinned best: 103.1-103.7us over
// three reproductions; kfused ~83us, VGPR 64+64acc = the 128-reg tier).
//
// PINNED STRUCTURE — verified by 10 failed variants (do not touch):
//  - quant FIRST in tile body (R16 reorder -> +8 VGPR -> cliff, +24us)
//  - rintf+cvt+shift/or quant formulation (R12 fma+perm, R13 magic-add
//    -> +4 VGPR -> cliff, +25us)
//  - BN=256 (R15's BN=128 -> per-tile overhead dominates, +61us)
//  - B via global_load_lds + counted vmcnt(2) (R5-R8 reg-B latency-exposed)
//  - plain stores (R18 nontemporal -> partial-line write amplification,
//    WRITE 131->182MB, +8us; FETCH unchanged -> eviction theory false)
//  - single-cluster 16-MFMA body (R1/R9 phase splits -> 17% MfmaUtil)

#define MK_M 32768
#define MK_K 1024
#define MK_N 1024

typedef __attribute__((ext_vector_type(4))) int int32x4;

// ---- workspace layout ----
#define WS_MAXP_OFF 64
#define WS_PART_OFF 8448
#define WS_QW_OFF 16384
#define WS_NEEDED (WS_QW_OFF + (1 << 20))

// fused: blocks [0,2048) -> per-block max|x|; blocks [2048,2112) -> partial sum|W|
__global__ void kprep(const float4* __restrict__ x4, const float4* __restrict__ w4,
                      float* __restrict__ maxp, double* __restrict__ partials, long n4x) {
    const int bid = blockIdx.x;
    if (bid < 2048) {
        float m = 0.f;
        const long stride = 2048L * 256;
        for (long i = (long)bid * 256 + threadIdx.x; i < n4x; i += stride) {
            float4 v = x4[i];
            m = fmaxf(m, fmaxf(fmaxf(fabsf(v.x), fabsf(v.y)), fmaxf(fabsf(v.z), fabsf(v.w))));
        }
        #pragma unroll
        for (int off = 1; off < 64; off <<= 1) m = fmaxf(m, __shfl_xor(m, off));
        __shared__ float sm[4];
        int lane = threadIdx.x & 63, wid = threadIdx.x >> 6;
        if (lane == 0) sm[wid] = m;
        __syncthreads();
        if (threadIdx.x == 0) maxp[bid] = fmaxf(fmaxf(sm[0], sm[1]), fmaxf(sm[2], sm[3]));
    } else {
        double s = 0.0;
        for (int i = (bid - 2048) * 256 + threadIdx.x; i < (1 << 18); i += 64 * 256) {
            float4 v = w4[i];
            s += (double)fabsf(v.x);
            s += (double)fabsf(v.y);
            s += (double)fabsf(v.z);
            s += (double)fabsf(v.w);
        }
        __shared__ double sd[256];
        sd[threadIdx.x] = s;
        __syncthreads();
        for (int h = 128; h > 0; h >>= 1) {
            if ((int)threadIdx.x < h) sd[threadIdx.x] += sd[threadIdx.x + h];
            __syncthreads();
        }
        if (threadIdx.x == 0) partials[bid - 2048] = sd[0];
    }
}

// every block redundantly reduces partials[64] in the SAME fixed order.
__global__ void kquant_w(const float4* __restrict__ w4, unsigned* __restrict__ qw,
                         const double* __restrict__ partials, float* __restrict__ wscp) {
    __shared__ double sws;
    if (threadIdx.x < 64) {
        double s = partials[threadIdx.x];
        #pragma unroll
        for (int off = 1; off < 64; off <<= 1) s += __shfl_xor(s, off);
        if (threadIdx.x == 0) sws = s;
    }
    __syncthreads();
    float wsc = (float)(sws / 1048576.0);   // mean|W| over 2^20 elements
    if (blockIdx.x == 0 && threadIdx.x == 0) *wscp = wsc;
    float thr = 0.5f * wsc;
    int stride = gridDim.x * blockDim.x;
    for (int i = blockIdx.x * blockDim.x + threadIdx.x; i < (1 << 18); i += stride) {
        float4 v = w4[i];
        int q0 = (fabsf(v.x) > thr) ? (v.x > 0.f ? 1 : -1) : 0;
        int q1 = (fabsf(v.y) > thr) ? (v.y > 0.f ? 1 : -1) : 0;
        int q2 = (fabsf(v.z) > thr) ? (v.z > 0.f ? 1 : -1) : 0;
        int q3 = (fabsf(v.w) > thr) ? (v.w > 0.f ? 1 : -1) : 0;
        qw[i] = (q0 & 0xff) | ((q1 & 0xff) << 8) | ((q2 & 0xff) << 16) | ((q3 & 0xff) << 24);
    }
}

// ---- fused quant-A + int8 GEMM (R10, best) ----
// Tile 128x256, BK=64, 8 waves (2Mx4N), wave = 64x64 (acc[4][4]).
__global__ __launch_bounds__(512, 2) void kfused(
    const float* __restrict__ x, const char* __restrict__ qw,
    const float* __restrict__ bias, const float* __restrict__ wscp,
    const float* __restrict__ maxp, float* __restrict__ out)
{
    __shared__ __align__(16) char As[2][8192];
    __shared__ __align__(16) char Bs[3][16384];
    __shared__ float smx[8];

    const int t = threadIdx.x;
    const int l = t & 63;
    const int w = t >> 6;          // 0..7
    const int wm = w >> 2;         // 0..1
    const int wn = w & 3;          // 0..3

    // XCD-bijective swizzle: 1024 blocks, 8 XCDs, 128 contiguous per XCD.
    const int bid = blockIdx.x;
    const int wg = (bid & 7) * 128 + (bid >> 3);
    const int tm = wg >> 2, tn = wg & 3;
    const long m0 = (long)tm * 128;
    const int n0 = tn * 256;

    // i_scale: redundant deterministic reduce of maxp[2048]
    float m = 0.f;
    #pragma unroll
    for (int j = 0; j < 4; ++j) m = fmaxf(m, maxp[t + 512 * j]);
    #pragma unroll
    for (int off = 1; off < 64; off <<= 1) m = fmaxf(m, __shfl_xor(m, off));
    if (l == 0) smx[w] = m;
    __syncthreads();
    const float mm = fmaxf(fmaxf(fmaxf(smx[0], smx[1]), fmaxf(smx[2], smx[3])),
                           fmaxf(fmaxf(smx[4], smx[5]), fmaxf(smx[6], smx[7])));
    const float isc = mm / 127.0f;
    const float rin = 1.0f / isc;

    // A staging: thread t -> row arow = t>>2 (0..127), 16 floats at k-offset
    // (t&3)*16 within each 64-float K-window.
    const int arow = t >> 2;
    const int ac = t & 3;
    const float4* gA4 = (const float4*)(x + (m0 + arow) * MK_K + ac * 16);
    const int adsw = (ac ^ ((arow >> 1) & 3));          // swizzled chunk
    char* const adst0 = (char*)As[0] + arow * 64 + adsw * 16;
    char* const adst1 = (char*)As[1] + arow * 64 + adsw * 16;

    // B staging (R2 pattern): unit = 128 rows x 64B = 8KB = 512thr x 16B
    const int gch = (t & 3) ^ ((t >> 3) & 3);
    const char* gBt = qw + ((long)n0 + (t >> 2)) * MK_K + gch * 16;
    auto stageB = [&](int kt1, int b) {
        char* dst = (char*)Bs[b] + t * 16;
        const char* src = gBt + kt1 * 64;
        __builtin_amdgcn_global_load_lds(
            (const __attribute__((address_space(1))) void*)src,
            (__attribute__((address_space(3))) void*)dst, 16, 0, 0);
        __builtin_amdgcn_global_load_lds(
            (const __attribute__((address_space(1))) void*)(src + 128L * MK_K),
            (__attribute__((address_space(3))) void*)(dst + 8192), 16, 0, 0);
    };

    float4 ar0, ar1, ar2, ar3;   // in-flight A fp32 (16 VGPR)
    auto issueA = [&](int kt1) {
        ar0 = gA4[kt1 * 16 + 0];
        ar1 = gA4[kt1 * 16 + 1];
        ar2 = gA4[kt1 * 16 + 2];
        ar3 = gA4[kt1 * 16 + 3];
    };
    auto quantA = [&](char* dst) {
        int p[4];
        float4 vv[4] = {ar0, ar1, ar2, ar3};
        #pragma unroll
        for (int q = 0; q < 4; ++q) {
            int i0 = (int)rintf(vv[q].x * rin);
            int i1 = (int)rintf(vv[q].y * rin);
            int i2 = (int)rintf(vv[q].z * rin);
            int i3 = (int)rintf(vv[q].w * rin);
            p[q] = (i0 & 0xff) | ((i1 & 0xff) << 8) | ((i2 & 0xff) << 16) | ((i3 & 0xff) << 24);
        }
        int32x4 pk = {p[0], p[1], p[2], p[3]};
        *(int32x4*)dst = pk;
    };

    int32x4 acc[4][4];
    #pragma unroll
    for (int mi = 0; mi < 4; ++mi)
        #pragma unroll
        for (int ni = 0; ni < 4; ++ni) acc[mi][ni] = (int32x4)0;

    // prologue: queue must end as [B(0)2, A(1)4, B(1)2]
    issueA(0);                 // A(0) [4]
    stageB(0, 0);              // B(0) [2]
    asm volatile("s_waitcnt vmcnt(2)" ::: "memory");   // A(0) done
    quantA(adst0);             // As[0] = A(0)
    issueA(1);                 // A(1) [4]
    stageB(1, 1);              // B(1) [2]

    for (int kt = 0; kt < 16; ++kt) {
        if (kt < 15) asm volatile("s_waitcnt vmcnt(2) lgkmcnt(0)" ::: "memory");
        else         asm volatile("s_waitcnt vmcnt(0) lgkmcnt(0)" ::: "memory");
        __builtin_amdgcn_s_barrier();

        if (kt < 15) quantA((kt & 1) ? adst0 : adst1);  // write A(kt+1) -> As[(kt+1)&1]
        if (kt < 14) {
            issueA(kt + 2);                              // A first (queue order!)
            stageB(kt + 2, (kt + 2) % 3);                // then B
        }

        const char* bufA = As[kt & 1];
        const char* bufB = Bs[kt % 3];
        int32x4 af[4], bf[4];
        #pragma unroll
        for (int i = 0; i < 4; ++i) {
            int row = wm * 64 + i * 16 + (l & 15);
            int ch = (l >> 4) ^ ((row >> 1) & 3);
            af[i] = *(const int32x4*)(bufA + row * 64 + ch * 16);
        }
        #pragma unroll
        for (int i = 0; i < 4; ++i) {
            int row = wn * 64 + i * 16 + (l & 15);
            int ch = (l >> 4) ^ ((row >> 1) & 3);
            bf[i] = *(const int32x4*)(bufB + row * 64 + ch * 16);
        }
        __builtin_amdgcn_s_setprio(1);
        #pragma unroll
        for (int mi = 0; mi < 4; ++mi)
            #pragma unroll
            for (int ni = 0; ni < 4; ++ni)
                acc[mi][ni] = __builtin_amdgcn_mfma_i32_16x16x64_i8(
                    af[mi], bf[ni], acc[mi][ni], 0, 0, 0);
        __builtin_amdgcn_s_setprio(0);
    }

    // epilogue: C/D layout col = lane&15, row = (lane>>4)*4 + reg (verified)
    const float wsc = *wscp;
    const int crow = (l >> 4) * 4;
    const int ccol = l & 15;
    #pragma unroll
    for (int mi = 0; mi < 4; ++mi) {
        #pragma unroll
        for (int ni = 0; ni < 4; ++ni) {
            long r0 = m0 + wm * 64 + mi * 16 + crow;
            int c = n0 + wn * 64 + ni * 16 + ccol;
            float b = bias[c];
            #pragma unroll
            for (int j = 0; j < 4; ++j) {
                out[(r0 + j) * MK_N + c] = ((float)acc[mi][ni][j] * wsc) * isc + b;
            }
        }
    }
}

extern "C" void kernel_launch(void* const* d_in, const int* in_sizes, int n_in,
                              void* d_out, int out_size, void* d_ws, size_t ws_size,
                              hipStream_t stream) {
    const float* x = (const float*)d_in[0];
    const float* wt = (const float*)d_in[1];
    const float* bias = (const float*)d_in[2];
    float* out = (float*)d_out;

    if (ws_size < WS_NEEDED) return;

    char* ws = (char*)d_ws;
    float* wscp = (float*)(ws + 0);
    float* maxp = (float*)(ws + WS_MAXP_OFF);
    double* partials = (double*)(ws + WS_PART_OFF);
    char* qw = ws + WS_QW_OFF;

    const long n_x = (long)in_sizes[0];   // 33554432
    const long n4_x = n_x >> 2;

    kprep<<<2112, 256, 0, stream>>>((const float4*)x, (const float4*)wt, maxp, partials, n4_x);
    kquant_w<<<256, 256, 0, stream>>>((const float4*)wt, (unsigned*)qw, partials, wscp);

    const int grid = (MK_M / 128) * (MK_N / 256);  // 1024
    kfused<<<grid, 512, 0, stream>>>(x, qw, bias, wscp, maxp, out);
}